// Round 2
// baseline (375.881 us; speedup 1.0000x reference)
//
#include <hip/hip_runtime.h>
#include <math.h>

#define NEGV 1000000000000.0f
#define LDSTR 68   // 64 + 4 pad: keeps 16B alignment for float4 LDS reads, breaks bank conflicts

// ---------------- Kernel 1: h = x@W1+b1; RoPE -> qw,kw; bias = (h@W2+b2)/2 ----------------
// (verbatim round-0 version — proven fast in the 358 µs config)
__global__ __launch_bounds__(256) void k1_fused(
    const float* __restrict__ x,    // (4096, 768)
    const float* __restrict__ W1,   // (768, 128)
    const float* __restrict__ b1,   // (128)
    const float* __restrict__ W2,   // (128, 32)
    const float* __restrict__ b2,   // (32)
    float* __restrict__ qw,         // (4096, 64)
    float* __restrict__ kw,         // (4096, 64)
    float* __restrict__ bias)       // (4, 32, 1024)
{
    __shared__ float xs[16][772];   // 16 rows x 768, +4 pad
    __shared__ float hs[16][132];
    const int t    = threadIdx.x;
    const int row0 = blockIdx.x * 16;

    // ---- stage x tile (16 x 768 = 48 KB) into LDS, float4 coalesced ----
    {
        const float4* xg = (const float4*)(x + (size_t)row0 * 768);
        #pragma unroll
        for (int it = 0; it < 12; ++it) {
            const int idx = t + it * 256;            // 0..3071
            const int r = idx / 192, c4 = idx - r * 192;
            const float4 v = xg[idx];
            *(float4*)&xs[r][c4 * 4] = v;
        }
    }
    __syncthreads();

    // ---- GEMM: thread = 2 rows x 4 cols ----
    const int jc = (t & 31) * 4;
    const int rg = (t >> 5) * 2;
    float accA[4] = {0.f,0.f,0.f,0.f};
    float accB[4] = {0.f,0.f,0.f,0.f};
    #pragma unroll 2
    for (int k = 0; k < 768; k += 4) {
        const float4 xa = *(const float4*)&xs[rg][k];
        const float4 xb = *(const float4*)&xs[rg + 1][k];
        const float xav[4] = {xa.x, xa.y, xa.z, xa.w};
        const float xbv[4] = {xb.x, xb.y, xb.z, xb.w};
        #pragma unroll
        for (int kk = 0; kk < 4; ++kk) {
            const float4 w = *(const float4*)&W1[(size_t)(k + kk) * 128 + jc];
            const float wv[4] = {w.x, w.y, w.z, w.w};
            #pragma unroll
            for (int c = 0; c < 4; ++c) {
                accA[c] = fmaf(xav[kk], wv[c], accA[c]);
                accB[c] = fmaf(xbv[kk], wv[c], accB[c]);
            }
        }
    }
    {
        const float4 bv = *(const float4*)&b1[jc];
        const float bvv[4] = {bv.x, bv.y, bv.z, bv.w};
        #pragma unroll
        for (int c = 0; c < 4; ++c) {
            hs[rg][jc + c]     = accA[c] + bvv[c];
            hs[rg + 1][jc + c] = accB[c] + bvv[c];
        }
    }
    __syncthreads();

    // ---- RoPE. qw[c]=h[2c], kw[c]=h[2c+1] ----
    for (int idx = t; idx < 16 * 64; idx += 256) {
        const int r = idx >> 6, c = idx & 63;
        const int rowg = row0 + r;
        const int s = rowg & 1023;
        const int f = c & 31;
        const float invf = exp2f(-0.4152410118609203f * (float)f); // 10000^(-f/32)
        const float ang = (float)s * invf;
        float sn, cs;
        sincosf(ang, &sn, &cs);
        const int   pc  = (c & 1) ? (c - 1) : (c + 1);
        const float sgn = (c & 1) ? sn : -sn;
        const float qv = fmaf(hs[r][2*c],     cs, hs[r][2*pc]     * sgn);
        const float kv = fmaf(hs[r][2*c + 1], cs, hs[r][2*pc + 1] * sgn);
        qw[(size_t)rowg * 64 + c] = qv;
        kw[(size_t)rowg * 64 + c] = kv;
    }

    // ---- bias[b][c][s] = (h[row] . W2[:,c] + b2[c]) * 0.5 ----
    for (int idx = t; idx < 16 * 32; idx += 256) {
        const int r = idx >> 5, c = idx & 31;
        const int rowg = row0 + r;
        const int s = rowg & 1023, bb = rowg >> 10;
        float a = 0.f;
        #pragma unroll 4
        for (int k = 0; k < 128; ++k)
            a = fmaf(hs[r][k], W2[k * 32 + c], a);
        bias[(size_t)(bb * 32 + c) * 1024 + s] = (a + b2[c]) * 0.5f;
    }
}

// ---------------- Kernel 2a: qk8[b][m][n] = (qw[m] . kw[n]) / 8 ----------------
// Round-0 k2's proven GEMM core, minus the 16-plane epilogue. 64x64 tile, 4x4/thread.
// Output only 16 MB -> ~10 us. grid (16,16,4).
__global__ __launch_bounds__(256) void k2a_qk(
    const float* __restrict__ qw, const float* __restrict__ kw,
    float* __restrict__ qk8)
{
    __shared__ float qs[64 * LDSTR];   // [k][m]
    __shared__ float ks[64 * LDSTR];   // [k][n]

    const int t  = threadIdx.x;
    const int n0 = blockIdx.x * 64;
    const int m0 = blockIdx.y * 64;
    const int b  = blockIdx.z;

    const float4* qg = (const float4*)(qw + (size_t)(b * 1024 + m0) * 64);
    const float4* kg = (const float4*)(kw + (size_t)(b * 1024 + n0) * 64);
    #pragma unroll
    for (int it = 0; it < 4; ++it) {
        const int idx = t + it * 256;          // 0..1023 ; = m*16 + kgp
        const int m = idx >> 4, kgp = idx & 15;
        float4 v = qg[idx];
        qs[(4*kgp + 0) * LDSTR + m] = v.x;
        qs[(4*kgp + 1) * LDSTR + m] = v.y;
        qs[(4*kgp + 2) * LDSTR + m] = v.z;
        qs[(4*kgp + 3) * LDSTR + m] = v.w;
        v = kg[idx];
        ks[(4*kgp + 0) * LDSTR + m] = v.x;
        ks[(4*kgp + 1) * LDSTR + m] = v.y;
        ks[(4*kgp + 2) * LDSTR + m] = v.z;
        ks[(4*kgp + 3) * LDSTR + m] = v.w;
    }
    __syncthreads();

    const int tn = t & 15, tm = t >> 4;
    float acc[4][4];
    #pragma unroll
    for (int i = 0; i < 4; ++i)
        #pragma unroll
        for (int c = 0; c < 4; ++c) acc[i][c] = 0.f;

    #pragma unroll 8
    for (int k = 0; k < 64; ++k) {
        const float4 qv = *(const float4*)&qs[k * LDSTR + 4 * tm];
        const float4 kv = *(const float4*)&ks[k * LDSTR + 4 * tn];
        const float qa[4] = {qv.x, qv.y, qv.z, qv.w};
        const float ka[4] = {kv.x, kv.y, kv.z, kv.w};
        #pragma unroll
        for (int i = 0; i < 4; ++i)
            #pragma unroll
            for (int c = 0; c < 4; ++c)
                acc[i][c] = fmaf(qa[i], ka[c], acc[i][c]);
    }

    const int ng = n0 + 4 * tn;
    #pragma unroll
    for (int i = 0; i < 4; ++i) {
        const int mg = m0 + 4 * tm + i;
        float4 r4;
        r4.x = acc[i][0] * 0.125f;
        r4.y = acc[i][1] * 0.125f;
        r4.z = acc[i][2] * 0.125f;
        r4.w = acc[i][3] * 0.125f;
        *(float4*)(qk8 + ((size_t)(b * 1024 + mg)) * 1024 + ng) = r4;
    }
}

// ---------------- Kernel 2b: fill-shaped broadcast ----------------
// out[b][o][m][n] = (qk8[b][m][n] + vb[o][m]) * p[n] + (av[o][n]*p[n] - (1-p[n])*NEG) - causal
// NO LDS, NO syncthreads, ~40 VGPR -> 32 waves/CU, pure streaming stores like the 6.2 TB/s fill.
// Thread t owns column float4 [4t..4t+3] for its block's 8 rows x 2 o-planes (o1, o1+8).
// grid (8, 128, 4) = 4096 blocks.
__global__ __launch_bounds__(256) void k2b_bcast(
    const float* __restrict__ qk8,  // (4, 1024, 1024)
    const float* __restrict__ bias, // (4, 32, 1024)
    const float* __restrict__ mask, // (4, 1024)
    float* __restrict__ out)        // (4, 16, 1024, 1024)
{
    const int t  = threadIdx.x;
    const int o1 = blockIdx.x;        // o = o1, o1+8
    const int m0 = blockIdx.y * 8;    // 8 rows
    const int b  = blockIdx.z;
    const int n  = 4 * t;

    const float4 pv = *(const float4*)&mask[b * 1024 + n];
    const float p[4] = {pv.x, pv.y, pv.z, pv.w};

    float Q[2][4];                     // av*p - (1-p)*NEG, per o-plane
    float vb[2][8];                    // bias[b][2o+1][m0..m0+7], wave-uniform
    #pragma unroll
    for (int s = 0; s < 2; ++s) {
        const int o = o1 + 8 * s;
        const float4 av = *(const float4*)&bias[(size_t)(b * 32 + 2 * o) * 1024 + n];
        const float a[4] = {av.x, av.y, av.z, av.w};
        #pragma unroll
        for (int c = 0; c < 4; ++c)
            Q[s][c] = a[c] * p[c] - (1.f - p[c]) * NEGV;
        const float4 v0 = *(const float4*)&bias[(size_t)(b * 32 + 2 * o + 1) * 1024 + m0];
        const float4 v1 = *(const float4*)&bias[(size_t)(b * 32 + 2 * o + 1) * 1024 + m0 + 4];
        vb[s][0] = v0.x; vb[s][1] = v0.y; vb[s][2] = v0.z; vb[s][3] = v0.w;
        vb[s][4] = v1.x; vb[s][5] = v1.y; vb[s][6] = v1.z; vb[s][7] = v1.w;
    }

    const float* qrow = qk8 + ((size_t)(b * 1024 + m0)) * 1024 + n;
    float* ob0 = out + ((size_t)((b * 16 + o1)     * 1024 + m0)) * 1024 + n;
    float* ob1 = out + ((size_t)((b * 16 + o1 + 8) * 1024 + m0)) * 1024 + n;

    #pragma unroll
    for (int r = 0; r < 8; ++r) {
        const int m = m0 + r;
        const float4 qv = *(const float4*)&qrow[(size_t)r * 1024];
        const float q[4] = {qv.x, qv.y, qv.z, qv.w};
        float cz[4];
        #pragma unroll
        for (int c = 0; c < 4; ++c)
            cz[c] = (n + c < m) ? NEGV : 0.f;   // tril(-1) causal

        float4 r0, r1;
        r0.x = fmaf(q[0] + vb[0][r], p[0], Q[0][0]) - cz[0];
        r0.y = fmaf(q[1] + vb[0][r], p[1], Q[0][1]) - cz[1];
        r0.z = fmaf(q[2] + vb[0][r], p[2], Q[0][2]) - cz[2];
        r0.w = fmaf(q[3] + vb[0][r], p[3], Q[0][3]) - cz[3];
        r1.x = fmaf(q[0] + vb[1][r], p[0], Q[1][0]) - cz[0];
        r1.y = fmaf(q[1] + vb[1][r], p[1], Q[1][1]) - cz[1];
        r1.z = fmaf(q[2] + vb[1][r], p[2], Q[1][2]) - cz[2];
        r1.w = fmaf(q[3] + vb[1][r], p[3], Q[1][3]) - cz[3];
        *(float4*)&ob0[(size_t)r * 1024] = r0;
        *(float4*)&ob1[(size_t)r * 1024] = r1;
    }
}

extern "C" void kernel_launch(void* const* d_in, const int* in_sizes, int n_in,
                              void* d_out, int out_size, void* d_ws, size_t ws_size,
                              hipStream_t stream) {
    const float* x    = (const float*)d_in[0];
    const float* mask = (const float*)d_in[1];
    const float* W1   = (const float*)d_in[2];
    const float* b1   = (const float*)d_in[3];
    const float* W2   = (const float*)d_in[4];
    const float* b2   = (const float*)d_in[5];
    float* out = (float*)d_out;

    float* ws   = (float*)d_ws;
    float* qw   = ws;                         // 4096*64
    float* kw   = ws + 4096 * 64;             // 4096*64
    float* bias = ws + 2 * 4096 * 64;         // 4*32*1024
    float* qk8  = ws + 2 * 4096 * 64 + 4 * 32 * 1024;   // 4*1024*1024 (16 MB)

    hipLaunchKernelGGL(k1_fused, dim3(256), dim3(256), 0, stream,
                       x, W1, b1, W2, b2, qw, kw, bias);
    hipLaunchKernelGGL(k2a_qk, dim3(16, 16, 4), dim3(256), 0, stream,
                       qw, kw, qk8);
    hipLaunchKernelGGL(k2b_bcast, dim3(8, 128, 4), dim3(256), 0, stream,
                       qk8, bias, mask, out);
}

// Round 4
// 353.956 us; speedup vs baseline: 1.0619x; 1.0619x over previous
//
#include <hip/hip_runtime.h>
#include <math.h>

#define NEGV 1000000000000.0f
#define LDSTR 68   // 64 + 4 pad: keeps 16B alignment for float4 LDS reads, breaks bank conflicts

typedef float v4f __attribute__((ext_vector_type(4)));   // native clang vector for nontemporal builtin

// ---------------- Kernel 1: h = x@W1+b1; RoPE -> qw,kw; bias = (h@W2+b2)/2 ----------------
// (verbatim round-0 version — proven fastest config at 358.5 us)
__global__ __launch_bounds__(256) void k1_fused(
    const float* __restrict__ x,    // (4096, 768)
    const float* __restrict__ W1,   // (768, 128)
    const float* __restrict__ b1,   // (128)
    const float* __restrict__ W2,   // (128, 32)
    const float* __restrict__ b2,   // (32)
    float* __restrict__ qw,         // (4096, 64)
    float* __restrict__ kw,         // (4096, 64)
    float* __restrict__ bias)       // (4, 32, 1024)
{
    __shared__ float xs[16][772];   // 16 rows x 768, +4 pad
    __shared__ float hs[16][132];
    const int t    = threadIdx.x;
    const int row0 = blockIdx.x * 16;

    // ---- stage x tile (16 x 768 = 48 KB) into LDS, float4 coalesced ----
    {
        const float4* xg = (const float4*)(x + (size_t)row0 * 768);
        #pragma unroll
        for (int it = 0; it < 12; ++it) {
            const int idx = t + it * 256;            // 0..3071
            const int r = idx / 192, c4 = idx - r * 192;
            const float4 v = xg[idx];
            *(float4*)&xs[r][c4 * 4] = v;
        }
    }
    __syncthreads();

    // ---- GEMM: thread = 2 rows x 4 cols. x from LDS (broadcast b128), W1 float4 VMEM ----
    const int jc = (t & 31) * 4;       // col group (4 consecutive cols of 128)
    const int rg = (t >> 5) * 2;       // row pair (0,2,4,..,14)
    float accA[4] = {0.f,0.f,0.f,0.f};
    float accB[4] = {0.f,0.f,0.f,0.f};
    #pragma unroll 2
    for (int k = 0; k < 768; k += 4) {
        const float4 xa = *(const float4*)&xs[rg][k];
        const float4 xb = *(const float4*)&xs[rg + 1][k];
        const float xav[4] = {xa.x, xa.y, xa.z, xa.w};
        const float xbv[4] = {xb.x, xb.y, xb.z, xb.w};
        #pragma unroll
        for (int kk = 0; kk < 4; ++kk) {
            const float4 w = *(const float4*)&W1[(size_t)(k + kk) * 128 + jc];
            const float wv[4] = {w.x, w.y, w.z, w.w};
            #pragma unroll
            for (int c = 0; c < 4; ++c) {
                accA[c] = fmaf(xav[kk], wv[c], accA[c]);
                accB[c] = fmaf(xbv[kk], wv[c], accB[c]);
            }
        }
    }
    {
        const float4 bv = *(const float4*)&b1[jc];
        const float bvv[4] = {bv.x, bv.y, bv.z, bv.w};
        #pragma unroll
        for (int c = 0; c < 4; ++c) {
            hs[rg][jc + c]     = accA[c] + bvv[c];
            hs[rg + 1][jc + c] = accB[c] + bvv[c];
        }
    }
    __syncthreads();

    // ---- RoPE. qw[c]=h[2c], kw[c]=h[2c+1] ----
    for (int idx = t; idx < 16 * 64; idx += 256) {
        const int r = idx >> 6, c = idx & 63;
        const int rowg = row0 + r;
        const int s = rowg & 1023;
        const int f = c & 31;
        const float invf = exp2f(-0.4152410118609203f * (float)f); // 10000^(-f/32)
        const float ang = (float)s * invf;
        float sn, cs;
        sincosf(ang, &sn, &cs);
        const int   pc  = (c & 1) ? (c - 1) : (c + 1);
        const float sgn = (c & 1) ? sn : -sn;
        const float qv = fmaf(hs[r][2*c],     cs, hs[r][2*pc]     * sgn);
        const float kv = fmaf(hs[r][2*c + 1], cs, hs[r][2*pc + 1] * sgn);
        qw[(size_t)rowg * 64 + c] = qv;
        kw[(size_t)rowg * 64 + c] = kv;
    }

    // ---- bias[b][c][s] = (h[row] . W2[:,c] + b2[c]) * 0.5 ----
    for (int idx = t; idx < 16 * 32; idx += 256) {
        const int r = idx >> 5, c = idx & 31;
        const int rowg = row0 + r;
        const int s = rowg & 1023, bb = rowg >> 10;
        float a = 0.f;
        #pragma unroll 4
        for (int k = 0; k < 128; ++k)
            a = fmaf(hs[r][k], W2[k * 32 + c], a);
        bias[(size_t)(bb * 32 + c) * 1024 + s] = (a + b2[c]) * 0.5f;
    }
}

// ---------------- Kernel 2: out[b,o,m,n] = qk/8 + bA[o][n] + bB[o][m], mask + causal ------
// grid (16,16,4) = (nTile, mTile, b); 256 threads; 64x64 (m,n) tile; 4x4 per thread.
// Verbatim round-0 structure; ONLY change: nontemporal out stores (out is write-once,
// never re-read -> skip L2 write-allocate, avoid evicting 4MB/XCD L2 8x over).
__global__ __launch_bounds__(256) void k2_outer(
    const float* __restrict__ qw, const float* __restrict__ kw,
    const float* __restrict__ bias, const float* __restrict__ mask,
    float* __restrict__ out)
{
    __shared__ float qs[64 * LDSTR];   // [k][m]
    __shared__ float ks[64 * LDSTR];   // [k][n]
    __shared__ float bA[16][64];       // bias[b][2o][n-tile]
    __shared__ float bB[16][64];       // bias[b][2o+1][m-tile]
    __shared__ float padv[64];

    const int t  = threadIdx.x;
    const int n0 = blockIdx.x * 64;
    const int m0 = blockIdx.y * 64;
    const int b  = blockIdx.z;

    const float4* qg = (const float4*)(qw + (size_t)(b * 1024 + m0) * 64);
    const float4* kg = (const float4*)(kw + (size_t)(b * 1024 + n0) * 64);
    #pragma unroll
    for (int it = 0; it < 4; ++it) {
        const int idx = t + it * 256;          // 0..1023 ; = m*16 + kgp
        const int m = idx >> 4, kgp = idx & 15;
        float4 v = qg[idx];
        qs[(4*kgp + 0) * LDSTR + m] = v.x;
        qs[(4*kgp + 1) * LDSTR + m] = v.y;
        qs[(4*kgp + 2) * LDSTR + m] = v.z;
        qs[(4*kgp + 3) * LDSTR + m] = v.w;
        v = kg[idx];
        ks[(4*kgp + 0) * LDSTR + m] = v.x;
        ks[(4*kgp + 1) * LDSTR + m] = v.y;
        ks[(4*kgp + 2) * LDSTR + m] = v.z;
        ks[(4*kgp + 3) * LDSTR + m] = v.w;
    }
    for (int idx = t; idx < 16 * 64; idx += 256) {
        const int o = idx >> 6, c = idx & 63;
        bA[o][c] = bias[(size_t)(b * 32 + 2*o)     * 1024 + n0 + c];
        bB[o][c] = bias[(size_t)(b * 32 + 2*o + 1) * 1024 + m0 + c];
    }
    if (t < 64) padv[t] = mask[b * 1024 + n0 + t];
    __syncthreads();

    const int tn = t & 15, tm = t >> 4;
    float acc[4][4];
    #pragma unroll
    for (int i = 0; i < 4; ++i)
        #pragma unroll
        for (int c = 0; c < 4; ++c) acc[i][c] = 0.f;

    #pragma unroll 8
    for (int k = 0; k < 64; ++k) {
        const float4 qv = *(const float4*)&qs[k * LDSTR + 4 * tm];
        const float4 kv = *(const float4*)&ks[k * LDSTR + 4 * tn];
        const float qa[4] = {qv.x, qv.y, qv.z, qv.w};
        const float ka[4] = {kv.x, kv.y, kv.z, kv.w};
        #pragma unroll
        for (int i = 0; i < 4; ++i)
            #pragma unroll
            for (int c = 0; c < 4; ++c)
                acc[i][c] = fmaf(qa[i], ka[c], acc[i][c]);
    }

    const float4 pv = *(const float4*)&padv[4 * tn];
    const float p[4] = {pv.x, pv.y, pv.z, pv.w};
    float negterm[4];
    #pragma unroll
    for (int c = 0; c < 4; ++c) negterm[c] = (1.f - p[c]) * NEGV;
    const int ng = n0 + 4 * tn;

    #pragma unroll
    for (int o = 0; o < 16; ++o) {
        const float4 av = *(const float4*)&bA[o][4 * tn];
        const float a[4] = {av.x, av.y, av.z, av.w};
        #pragma unroll
        for (int i = 0; i < 4; ++i) {
            const int mg = m0 + 4 * tm + i;
            const float vb = bB[o][4 * tm + i];
            float rv[4];
            #pragma unroll
            for (int c = 0; c < 4; ++c) {
                float v = fmaf(acc[i][c], 0.125f, a[c] + vb);
                v = v * p[c] - negterm[c];
                if (ng + c < mg) v -= NEGV;   // tril(-1) causal mask
                rv[c] = v;
            }
            v4f r4;
            r4.x = rv[0]; r4.y = rv[1]; r4.z = rv[2]; r4.w = rv[3];
            __builtin_nontemporal_store(
                r4, (v4f*)(out + ((size_t)((b * 16 + o) * 1024 + mg)) * 1024 + ng));
        }
    }
}

extern "C" void kernel_launch(void* const* d_in, const int* in_sizes, int n_in,
                              void* d_out, int out_size, void* d_ws, size_t ws_size,
                              hipStream_t stream) {
    const float* x    = (const float*)d_in[0];
    const float* mask = (const float*)d_in[1];
    const float* W1   = (const float*)d_in[2];
    const float* b1   = (const float*)d_in[3];
    const float* W2   = (const float*)d_in[4];
    const float* b2   = (const float*)d_in[5];
    float* out = (float*)d_out;

    float* ws   = (float*)d_ws;
    float* qw   = ws;                       // 4096*64 floats
    float* kw   = ws + 4096 * 64;           // 4096*64 floats
    float* bias = ws + 2 * 4096 * 64;       // 4*32*1024 floats  (total ~2.6 MB)

    hipLaunchKernelGGL(k1_fused, dim3(256), dim3(256), 0, stream,
                       x, W1, b1, W2, b2, qw, kw, bias);
    hipLaunchKernelGGL(k2_outer, dim3(16, 16, 4), dim3(256), 0, stream,
                       qw, kw, bias, mask, out);
}